// Round 7
// baseline (619.107 us; speedup 1.0000x reference)
//
#include <hip/hip_runtime.h>
#include <math.h>

#define B_    32
#define CIN   256
#define HID   256
#define OC    65
#define A_    9
#define H_    56
#define W_    56
#define HW    3136
#define AHW   28224
#define NBOX  64
#define M_    2048
#define CNUM  20
#define NTILE 49         // HW / 64
#define NTILES_TOT (B_ * NTILE)              // 1568

#define IOU_N ((size_t)B_ * AHW * NBOX)      // 57,802,752

// workspace byte offsets (total < 1 MB — well inside proven-safe territory)
#define WS_W1S   0
#define WS_W2S   131072
#define WS_LOSS  172032
#define WS_PCNT  172288
#define WS_NCNT  178560
#define WS_PBUF  184832
#define WS_NBUF  586240

// padded LDS fragment offset (halfwords): +16B every 8 fragment rows.
#define FOFF(frag) (((frag) << 3) + ((((frag) >> 3)) << 3))

typedef _Float16 half8 __attribute__((ext_vector_type(8)));
typedef float f32x16 __attribute__((ext_vector_type(16)));
typedef float f32x4  __attribute__((ext_vector_type(4)));

__device__ __forceinline__ unsigned int pkh(float a, float b) {
    _Float16 ha = (_Float16)a, hb = (_Float16)b;
    unsigned short ua = __builtin_bit_cast(unsigned short, ha);
    unsigned short ub = __builtin_bit_cast(unsigned short, hb);
    return (unsigned int)ua | ((unsigned int)ub << 16);
}

__global__ __launch_bounds__(256) void zero_kernel(int* __restrict__ cnts,
                                                   float* __restrict__ loss_ws) {
    const int i = blockIdx.x * 256 + threadIdx.x;
    if (i < 2 * NTILES_TOT) cnts[i] = 0;
    if (i < 2) loss_ws[i] = 0.f;
}

// Pre-swizzle weights into MFMA A-fragment order (fp16); bucket pos/neg indices by tile.
__global__ __launch_bounds__(256) void prep_kernel(
    const float* __restrict__ w1, const float* __restrict__ w2,
    _Float16* __restrict__ w1s, _Float16* __restrict__ w2s,
    const int* __restrict__ pos_idx, const int* __restrict__ neg_idx,
    int* __restrict__ pcnt, int* __restrict__ ncnt,
    int* __restrict__ pbuf, int* __restrict__ nbuf)
{
    const int f = blockIdx.x * 256 + threadIdx.x;   // 0..65535
    {
        const int e    = f & 7;
        const int lane = (f >> 3) & 63;
        const int kc   = (f >> 9) & 15;
        const int ob   = f >> 13;
        const int row  = ob * 32 + (lane & 31);
        const int k    = kc * 16 + (lane >> 5) * 8 + e;
        w1s[f] = (_Float16)w1[row * CIN + k];
    }
    if (f < 20480) {
        const int e    = f & 7;
        const int lane = (f >> 3) & 63;
        const int ks2  = (f >> 9) & 7;
        const int rt   = f >> 12;
        const int row  = rt * 16 + (lane & 15);
        const int k    = ks2 * 32 + (lane >> 4) * 8 + e;
        w2s[f] = (row < OC) ? (_Float16)w2[row * HID + k] : (_Float16)0.f;
    }
    if (f < 2 * M_) {
        const int m   = f & (M_ - 1);
        const int idx = (f < M_) ? pos_idx[m] : neg_idx[m];
        const int bi  = idx / AHW;
        const int rr  = idx - bi * AHW;
        const int a   = rr / HW;
        const int hw  = rr - a * HW;
        const int tile = bi * NTILE + (hw >> 6);
        const int enc  = m | (a << 11) | ((hw & 63) << 15);
        if (f < M_) {
            const int s = atomicAdd(&pcnt[tile], 1);
            if (s < 64) pbuf[tile * 64 + s] = enc;
        } else {
            const int s = atomicAdd(&ncnt[tile], 1);
            if (s < 64) nbuf[tile * 64 + s] = enc;
        }
    }
}

// ===== ABLATION PROBE 1: front-end only (staging+conv1+repack+conv2), x3 reps.
// Results kept alive via asm sink; writes nothing. Dispatch time = 3x front cost.
__global__ __launch_bounds__(256) void probe_front(
    const float* __restrict__ features, const _Float16* __restrict__ w1s,
    const float* __restrict__ b1, const _Float16* __restrict__ w2s)
{
    __shared__ _Float16 lds_h[18432];
    __shared__ float bias_s[HID];

    _Float16* featAll = lds_h;
    _Float16* hidf    = lds_h;

    const int t    = threadIdx.x;
    const int lane = t & 63;
    const int w    = t >> 6;
    const int bid  = blockIdx.x;
    const int b0   = bid / NTILE;
    const int p0   = (bid - b0 * NTILE) * 64;

    bias_s[t] = b1[t];

    const int pstage = (t & 15) * 4;
    const int kk     = (t >> 4) * 2;
    const int ksS    = kk >> 4;
    const int gS     = (kk >> 3) & 1;
    const int j0h    = kk & 7;
    const int ghalf  = lane >> 5;

    for (int r = 0; r < 3; ++r) {
        const int b = (b0 + r * 11) & 31;
        const float* fbase = features + (size_t)b * CIN * HW + p0;
        __syncthreads();   // protect LDS reuse across reps

#pragma unroll
        for (int hf = 0; hf < 2; ++hf) {
            float4 r0[4], r1[4];
#pragma unroll
            for (int c4 = 0; c4 < 4; ++c4) {
                const int c = hf * 4 + c4;
                r0[c4] = *(const float4*)(fbase + (size_t)(c * 32 + kk) * HW + pstage);
                r1[c4] = *(const float4*)(fbase + (size_t)(c * 32 + kk + 1) * HW + pstage);
            }
#pragma unroll
            for (int c4 = 0; c4 < 4; ++c4) {
                const int c = hf * 4 + c4;
                const float a0[4] = {r0[c4].x, r0[c4].y, r0[c4].z, r0[c4].w};
                const float a1[4] = {r1[c4].x, r1[c4].y, r1[c4].z, r1[c4].w};
#pragma unroll
                for (int e = 0; e < 4; ++e) {
                    const int p     = pstage + e;
                    const int lane2 = gS * 32 + (p & 31);
                    const int pt    = p >> 5;
                    const int frag  = c * 256 + (ksS * 2 + pt) * 64 + lane2;
                    *(unsigned int*)&featAll[FOFF(frag) + j0h] = pkh(a0[e], a1[e]);
                }
            }
        }
        __syncthreads();

        f32x16 facc[2][2];
#pragma unroll
        for (int ot = 0; ot < 2; ++ot)
#pragma unroll
            for (int pt = 0; pt < 2; ++pt)
#pragma unroll
                for (int e = 0; e < 16; ++e) facc[ot][pt][e] = 0.f;

        half8 afb[2][2][2];
#pragma unroll
        for (int ks = 0; ks < 2; ++ks)
#pragma unroll
            for (int ot = 0; ot < 2; ++ot)
                afb[0][ks][ot] = *(const half8*)(w1s + ((size_t)((w * 2 + ot) * 16 + ks) * 64 + lane) * 8);

#pragma unroll
        for (int c = 0; c < 8; ++c) {
            if (c < 7) {
#pragma unroll
                for (int ks = 0; ks < 2; ++ks)
#pragma unroll
                    for (int ot = 0; ot < 2; ++ot)
                        afb[(c + 1) & 1][ks][ot] =
                            *(const half8*)(w1s + ((size_t)((w * 2 + ot) * 16 + (c + 1) * 2 + ks) * 64 + lane) * 8);
            }
#pragma unroll
            for (int ks = 0; ks < 2; ++ks) {
#pragma unroll
                for (int pt = 0; pt < 2; ++pt) {
                    const half8 bf = *(const half8*)&featAll[FOFF(c * 256 + (ks * 2 + pt) * 64 + lane)];
                    facc[0][pt] = __builtin_amdgcn_mfma_f32_32x32x16_f16(afb[c & 1][ks][0], bf, facc[0][pt], 0, 0, 0);
                    facc[1][pt] = __builtin_amdgcn_mfma_f32_32x32x16_f16(afb[c & 1][ks][1], bf, facc[1][pt], 0, 0, 0);
                }
            }
        }
        __syncthreads();

        const int col = lane & 31;
#pragma unroll
        for (int ot = 0; ot < 2; ++ot) {
            const int ks2 = w * 2 + ot;
#pragma unroll
            for (int pt = 0; pt < 2; ++pt) {
                const int pt2 = pt * 2 + (col >> 4);
                const int n15 = col & 15;
#pragma unroll
                for (int q = 0; q < 4; ++q) {
                    float hv[4];
#pragma unroll
                    for (int i = 0; i < 4; ++i) {
                        const int row = i + 8 * q + 4 * ghalf;
                        float v = facc[ot][pt][q * 4 + i] + bias_s[w * 64 + ot * 32 + row];
                        hv[i] = v < 0.f ? 0.01f * v : v;
                    }
                    const int frag = (ks2 * 4 + pt2) * 64 + (q * 16 + n15);
                    *(unsigned int*)&hidf[FOFF(frag) + 4 * ghalf]     = pkh(hv[0], hv[1]);
                    *(unsigned int*)&hidf[FOFF(frag) + 4 * ghalf + 2] = pkh(hv[2], hv[3]);
                }
            }
        }
        __syncthreads();

        f32x4 c2[5];
#pragma unroll
        for (int rt = 0; rt < 5; ++rt)
#pragma unroll
            for (int e = 0; e < 4; ++e) c2[rt][e] = 0.f;

        half8 afc[2][5];
#pragma unroll
        for (int rt = 0; rt < 5; ++rt)
            afc[0][rt] = *(const half8*)(w2s + ((size_t)(rt * 8) * 64 + lane) * 8);

#pragma unroll
        for (int ks2 = 0; ks2 < 8; ++ks2) {
            if (ks2 < 7) {
#pragma unroll
                for (int rt = 0; rt < 5; ++rt)
                    afc[(ks2 + 1) & 1][rt] =
                        *(const half8*)(w2s + ((size_t)(rt * 8 + ks2 + 1) * 64 + lane) * 8);
            }
            const half8 bf = *(const half8*)&hidf[FOFF((ks2 * 4 + w) * 64 + lane)];
#pragma unroll
            for (int rt = 0; rt < 5; ++rt)
                c2[rt] = __builtin_amdgcn_mfma_f32_16x16x32_f16(afc[ks2 & 1][rt], bf, c2[rt], 0, 0, 0);
        }

        // keep-alive sink (rule #17): prevents DCE of the whole chain
        float s = 0.f;
#pragma unroll
        for (int rt = 0; rt < 5; ++rt)
#pragma unroll
            for (int e = 0; e < 4; ++e) s += c2[rt][e];
        asm volatile("" :: "v"(s));
    }
}

// ===== ABLATION PROBE 2: standalone LDS->IoU->store, x4 reps, junk proposals.
// Runs BEFORE conv_iou_kernel, which overwrites every element with correct
// values — so junk output is harmless. Dispatch time = 4x IoU-phase cost.
__global__ __launch_bounds__(256) void probe_iou(
    const float* __restrict__ bboxes, float* __restrict__ iou_out)
{
    __shared__ float P[5 * 64];
    __shared__ float boxs[5 * 64];

    const int t    = threadIdx.x;
    const int lane = t & 63;
    const int w    = t >> 6;
    const int bid  = blockIdx.x;
    const int b    = bid / (A_ * NTILE);
    const int r_   = bid - b * (A_ * NTILE);
    const int a    = r_ / NTILE;
    const int p0   = (r_ - a * NTILE) * 64;

    const size_t pbase = ((size_t)b * A_ + a) * HW + p0;

    if (t < 64) {
        const float* gb = bboxes + ((size_t)b * NBOX + t) * 5;
        const float x1 = gb[0], y1 = gb[1], x2v = gb[2], y2v = gb[3];
        boxs[t] = x1; boxs[64 + t] = y1; boxs[128 + t] = x2v; boxs[192 + t] = y2v;
        boxs[256 + t] = (x2v - x1) * (y2v - y1);
    }
    // junk proposals, un-foldable (depend on bid)
    for (int i = t; i < 320; i += 256) {
        P[i] = (float)(((unsigned)(bid * 131 + i) * 2654435761u) >> 16) * 1e-4f;
    }
    __syncthreads();

    const int pr = lane >> 4;
    const int j0 = (lane & 15) * 4;
    float Bx1[4], By1[4], Bx2[4], By2[4], Ba[4];
#pragma unroll
    for (int e = 0; e < 4; ++e) {
        Bx1[e] = boxs[j0 + e];       By1[e] = boxs[64 + j0 + e];
        Bx2[e] = boxs[128 + j0 + e]; By2[e] = boxs[192 + j0 + e];
        Ba[e]  = boxs[256 + j0 + e];
    }

    float* ibase = iou_out + pbase * 64;
#pragma unroll 1
    for (int rep = 0; rep < 4; ++rep) {
#pragma unroll
        for (int q = 0; q < 4; ++q) {
            const int p = w * 16 + q * 4 + pr;
            const float Px1 = P[p], Py1 = P[64 + p], Px2 = P[128 + p], Py2 = P[192 + p];
            const float pa  = P[256 + p];
            f32x4 o4;
#pragma unroll
            for (int e = 0; e < 4; ++e) {
                const float iw = fminf(Px2, Bx2[e]) - fmaxf(Px1, Bx1[e]);
                const float ih = fminf(Py2, By2[e]) - fmaxf(Py1, By1[e]);
                const float inter = fmaxf(iw, 0.f) * fmaxf(ih, 0.f);
                o4[e] = inter * __builtin_amdgcn_rcpf(Ba[e] + pa - inter);
            }
            float v0 = o4[0], v1 = o4[1], v2 = o4[2], v3 = o4[3];
            asm volatile("" : "+v"(v0), "+v"(v1), "+v"(v2), "+v"(v3));
            o4[0] = v0; o4[1] = v1; o4[2] = v2; o4[3] = v3;
            *(f32x4*)(ibase + (size_t)p * 64 + j0) = o4;
        }
        asm volatile("" ::: "memory");   // no store CSE across reps
    }
}

// Fused conv1 + conv2 + IoU + bucketed loss/class tail (round-5 body + buckets).
__global__ __launch_bounds__(256) void conv_iou_kernel(
    const float* __restrict__ features, const _Float16* __restrict__ w1s,
    const float* __restrict__ b1, const _Float16* __restrict__ w2s,
    const float* __restrict__ b2, const float* __restrict__ anc,
    const float* __restrict__ bboxes,
    const int* __restrict__ pcnt, const int* __restrict__ ncnt,
    const int* __restrict__ pbuf, const int* __restrict__ nbuf,
    const float* __restrict__ gt_off,
    float* __restrict__ iou_out, float* __restrict__ cls_out,
    float* __restrict__ loss_ws)
{
    __shared__ _Float16 lds_h[18432];   // 36 KB: feat frags -> hidf -> x2t+WP
    __shared__ float bias_s[HID];
    __shared__ float boxs[5 * 64];
    __shared__ float red[8];

    _Float16* featAll = lds_h;
    _Float16* hidf    = lds_h;
    float*    L       = (float*)lds_h;
    float*    x2t     = L;              // 64*69 floats

    const int t    = threadIdx.x;
    const int lane = t & 63;
    const int w    = t >> 6;
    const int bid  = blockIdx.x;
    const int b    = bid / NTILE;
    const int p0   = (bid - b * NTILE) * 64;
    const float* fbase = features + (size_t)b * CIN * HW + p0;

    float* WPw = L + 4416 + w * 720;    // per-wave proposals: 5 planes x 144

    bias_s[t] = b1[t];
    if (t < 64) {
        const float* gb = bboxes + ((size_t)b * NBOX + t) * 5;
        const float x1 = gb[0], y1 = gb[1], x2v = gb[2], y2v = gb[3];
        boxs[t] = x1; boxs[64 + t] = y1; boxs[128 + t] = x2v; boxs[192 + t] = y2v;
        boxs[256 + t] = (x2v - x1) * (y2v - y1);
    }

    const int pstage = (t & 15) * 4;
    const int kk     = (t >> 4) * 2;
    const int ksS    = kk >> 4;
    const int gS     = (kk >> 3) & 1;
    const int j0h    = kk & 7;
    const int ghalf  = lane >> 5;

    // ---- stage ALL 8 feature chunks, fp32->fp16, padded fragment order ----
#pragma unroll
    for (int hf = 0; hf < 2; ++hf) {
        float4 r0[4], r1[4];
#pragma unroll
        for (int c4 = 0; c4 < 4; ++c4) {
            const int c = hf * 4 + c4;
            r0[c4] = *(const float4*)(fbase + (size_t)(c * 32 + kk) * HW + pstage);
            r1[c4] = *(const float4*)(fbase + (size_t)(c * 32 + kk + 1) * HW + pstage);
        }
#pragma unroll
        for (int c4 = 0; c4 < 4; ++c4) {
            const int c = hf * 4 + c4;
            const float a0[4] = {r0[c4].x, r0[c4].y, r0[c4].z, r0[c4].w};
            const float a1[4] = {r1[c4].x, r1[c4].y, r1[c4].z, r1[c4].w};
#pragma unroll
            for (int e = 0; e < 4; ++e) {
                const int p     = pstage + e;
                const int lane2 = gS * 32 + (p & 31);
                const int pt    = p >> 5;
                const int frag  = c * 256 + (ksS * 2 + pt) * 64 + lane2;
                *(unsigned int*)&featAll[FOFF(frag) + j0h] = pkh(a0[e], a1[e]);
            }
        }
    }
    __syncthreads();

    // ---- conv1 ----
    f32x16 facc[2][2];
#pragma unroll
    for (int ot = 0; ot < 2; ++ot)
#pragma unroll
        for (int pt = 0; pt < 2; ++pt)
#pragma unroll
            for (int e = 0; e < 16; ++e) facc[ot][pt][e] = 0.f;

    half8 afb[2][2][2];
#pragma unroll
    for (int ks = 0; ks < 2; ++ks)
#pragma unroll
        for (int ot = 0; ot < 2; ++ot)
            afb[0][ks][ot] = *(const half8*)(w1s + ((size_t)((w * 2 + ot) * 16 + ks) * 64 + lane) * 8);

#pragma unroll
    for (int c = 0; c < 8; ++c) {
        if (c < 7) {
#pragma unroll
            for (int ks = 0; ks < 2; ++ks)
#pragma unroll
                for (int ot = 0; ot < 2; ++ot)
                    afb[(c + 1) & 1][ks][ot] =
                        *(const half8*)(w1s + ((size_t)((w * 2 + ot) * 16 + (c + 1) * 2 + ks) * 64 + lane) * 8);
        }
#pragma unroll
        for (int ks = 0; ks < 2; ++ks) {
#pragma unroll
            for (int pt = 0; pt < 2; ++pt) {
                const half8 bf = *(const half8*)&featAll[FOFF(c * 256 + (ks * 2 + pt) * 64 + lane)];
                facc[0][pt] = __builtin_amdgcn_mfma_f32_32x32x16_f16(afb[c & 1][ks][0], bf, facc[0][pt], 0, 0, 0);
                facc[1][pt] = __builtin_amdgcn_mfma_f32_32x32x16_f16(afb[c & 1][ks][1], bf, facc[1][pt], 0, 0, 0);
            }
        }
    }
    __syncthreads();

    // ---- bias + leaky relu, repack ----
    const int col = lane & 31;
#pragma unroll
    for (int ot = 0; ot < 2; ++ot) {
        const int ks2 = w * 2 + ot;
#pragma unroll
        for (int pt = 0; pt < 2; ++pt) {
            const int pt2 = pt * 2 + (col >> 4);
            const int n15 = col & 15;
#pragma unroll
            for (int q = 0; q < 4; ++q) {
                float hv[4];
#pragma unroll
                for (int i = 0; i < 4; ++i) {
                    const int row = i + 8 * q + 4 * ghalf;
                    float v = facc[ot][pt][q * 4 + i] + bias_s[w * 64 + ot * 32 + row];
                    hv[i] = v < 0.f ? 0.01f * v : v;
                }
                const int frag = (ks2 * 4 + pt2) * 64 + (q * 16 + n15);
                *(unsigned int*)&hidf[FOFF(frag) + 4 * ghalf]     = pkh(hv[0], hv[1]);
                *(unsigned int*)&hidf[FOFF(frag) + 4 * ghalf + 2] = pkh(hv[2], hv[3]);
            }
        }
    }
    __syncthreads();

    // ---- conv2 ----
    f32x4 c2[5];
#pragma unroll
    for (int rt = 0; rt < 5; ++rt)
#pragma unroll
        for (int e = 0; e < 4; ++e) c2[rt][e] = 0.f;

    const int m16 = lane & 15;
    const int kgr = lane >> 4;

    half8 afc[2][5];
#pragma unroll
    for (int rt = 0; rt < 5; ++rt)
        afc[0][rt] = *(const half8*)(w2s + ((size_t)(rt * 8) * 64 + lane) * 8);

#pragma unroll
    for (int ks2 = 0; ks2 < 8; ++ks2) {
        if (ks2 < 7) {
#pragma unroll
            for (int rt = 0; rt < 5; ++rt)
                afc[(ks2 + 1) & 1][rt] =
                    *(const half8*)(w2s + ((size_t)(rt * 8 + ks2 + 1) * 64 + lane) * 8);
        }
        const half8 bf = *(const half8*)&hidf[FOFF((ks2 * 4 + w) * 64 + lane)];
#pragma unroll
        for (int rt = 0; rt < 5; ++rt)
            c2[rt] = __builtin_amdgcn_mfma_f32_16x16x32_f16(afc[ks2 & 1][rt], bf, c2[rt], 0, 0, 0);
    }
    __syncthreads();   // all hidf reads done; alias LDS as x2t + WP

    // ---- x2 tile (wave-local rows) ----
    const int pxl = w * 16 + m16;
#pragma unroll
    for (int rt = 0; rt < 5; ++rt) {
#pragma unroll
        for (int r = 0; r < 4; ++r) {
            const int o2 = rt * 16 + kgr * 4 + r;
            if (o2 < OC) x2t[pxl * 69 + o2] = c2[rt][r] + b2[o2];
        }
    }
    asm volatile("" ::: "memory");

    // ---- proposals for THIS wave's 16 pixels x 9 anchors ----
    for (int i = lane; i < A_ * 16; i += 64) {
        const int a  = i >> 4;
        const int pw = i & 15;
        const float* xr = x2t + (w * 16 + pw) * 69 + 5 * a;
        const float tx = xr[1], ty = xr[2], tw = xr[3], th = xr[4];
        const int hwg = p0 + w * 16 + pw;
        const int h   = hwg / W_;
        const int wv  = hwg - h * W_;
        const float gx = (float)wv + 0.5f;
        const float gy = (float)h + 0.5f;
        const float nw = anc[2 * a]     * __expf(tw);
        const float nh = anc[2 * a + 1] * __expf(th);
        const float cx = gx + tx, cy = gy + ty;
        WPw[i]       = cx - 0.5f * nw;
        WPw[144 + i] = cy - 0.5f * nh;
        WPw[288 + i] = cx + 0.5f * nw;
        WPw[432 + i] = cy + 0.5f * nh;
        WPw[576 + i] = nw * nh;
    }
    asm volatile("" ::: "memory");

    // ---- IoU stream-out: wave-private, batched LDS reads per anchor ----
    const int pr = lane >> 4;
    const int j0 = (lane & 15) * 4;
    float Bx1[4], By1[4], Bx2[4], By2[4], Ba[4];
#pragma unroll
    for (int e = 0; e < 4; ++e) {
        Bx1[e] = boxs[j0 + e];       By1[e] = boxs[64 + j0 + e];
        Bx2[e] = boxs[128 + j0 + e]; By2[e] = boxs[192 + j0 + e];
        Ba[e]  = boxs[256 + j0 + e];
    }
    float* ibase = iou_out + ((size_t)b * AHW + p0) * 64;
#pragma unroll 1
    for (int a = 0; a < A_; ++a) {
        float Px1[4], Py1[4], Px2[4], Py2[4], Pa[4];
#pragma unroll
        for (int q = 0; q < 4; ++q) {
            const int idx = a * 16 + q * 4 + pr;
            Px1[q] = WPw[idx];       Py1[q] = WPw[144 + idx];
            Px2[q] = WPw[288 + idx]; Py2[q] = WPw[432 + idx];
            Pa[q]  = WPw[576 + idx];
        }
#pragma unroll
        for (int q = 0; q < 4; ++q) {
            f32x4 o4;
#pragma unroll
            for (int e = 0; e < 4; ++e) {
                const float iw = fminf(Px2[q], Bx2[e]) - fmaxf(Px1[q], Bx1[e]);
                const float ih = fminf(Py2[q], By2[e]) - fmaxf(Py1[q], By1[e]);
                const float inter = fmaxf(iw, 0.f) * fmaxf(ih, 0.f);
                o4[e] = inter * __builtin_amdgcn_rcpf(Ba[e] + Pa[q] - inter);
            }
            *(f32x4*)(ibase + ((size_t)(a * HW) + w * 16 + q * 4 + pr) * 64 + j0) = o4;
        }
    }

    // ---- bucketed loss/class tail ----
    __syncthreads();

    float csum = 0.f, rsum = 0.f;
    {
        int np = pcnt[bid]; np = np > 64 ? 64 : np;
        for (int i = t; i < np; i += 256) {
            const int e  = pbuf[bid * 64 + i];
            const int m  = e & 2047;
            const int a  = (e >> 11) & 15;
            const int px = (e >> 15) & 63;
            const float* xr = x2t + px * 69;
            const float s = 1.f / (1.f + __expf(-xr[5 * a]));
            csum += (s - 1.f) * (s - 1.f);
#pragma unroll
            for (int k = 0; k < 4; ++k) {
                const float d = xr[5 * a + 1 + k] - gt_off[m * 4 + k];
                rsum += d * d;
            }
            float* co = cls_out + (size_t)m * CNUM;
#pragma unroll
            for (int c = 0; c < CNUM; ++c) co[c] = xr[45 + c];
        }
        int nn = ncnt[bid]; nn = nn > 64 ? 64 : nn;
        for (int i = t; i < nn; i += 256) {
            const int e  = nbuf[bid * 64 + i];
            const int a  = (e >> 11) & 15;
            const int px = (e >> 15) & 63;
            const float s = 1.f / (1.f + __expf(-x2t[px * 69 + 5 * a]));
            csum += s * s;
        }
    }
#pragma unroll
    for (int off = 32; off > 0; off >>= 1) {
        csum += __shfl_down(csum, off, 64);
        rsum += __shfl_down(rsum, off, 64);
    }
    if (lane == 0) { red[w] = csum; red[4 + w] = rsum; }
    __syncthreads();
    if (t == 0) {
        const float c  = red[0] + red[1] + red[2] + red[3];
        const float rg = red[4] + red[5] + red[6] + red[7];
        if (c != 0.f || rg != 0.f) {
            atomicAdd(&loss_ws[0], c);
            atomicAdd(&loss_ws[1], rg);
        }
    }
}

__global__ void finalize_kernel(const float* __restrict__ loss_ws, float* __restrict__ out0)
{
    out0[0] = loss_ws[0] / (2.f * (float)M_) + loss_ws[1] / (float)M_;
}

extern "C" void kernel_launch(void* const* d_in, const int* in_sizes, int n_in,
                              void* d_out, int out_size, void* d_ws, size_t ws_size,
                              hipStream_t stream) {
    (void)in_sizes; (void)n_in; (void)out_size; (void)ws_size;
    const float* features = (const float*)d_in[0];
    const float* w1       = (const float*)d_in[1];
    const float* b1       = (const float*)d_in[2];
    const float* w2       = (const float*)d_in[3];
    const float* b2       = (const float*)d_in[4];
    const float* anc      = (const float*)d_in[5];
    const float* bboxes   = (const float*)d_in[7];
    const float* gt_off   = (const float*)d_in[8];
    const int*   pos_idx  = (const int*)d_in[9];
    const int*   neg_idx  = (const int*)d_in[10];
    float* out = (float*)d_out;

    char* wsb = (char*)d_ws;
    _Float16* w1s  = (_Float16*)(wsb + WS_W1S);
    _Float16* w2s  = (_Float16*)(wsb + WS_W2S);
    float* loss_ws = (float*)(wsb + WS_LOSS);
    int*   pcnt    = (int*)(wsb + WS_PCNT);
    int*   ncnt    = (int*)(wsb + WS_NCNT);
    int*   pbuf    = (int*)(wsb + WS_PBUF);
    int*   nbuf    = (int*)(wsb + WS_NBUF);

    zero_kernel<<<13, 256, 0, stream>>>(pcnt, loss_ws);
    prep_kernel<<<256, 256, 0, stream>>>(w1, w2, w1s, w2s, pos_idx, neg_idx,
                                         pcnt, ncnt, pbuf, nbuf);
    // Probes run BEFORE the real kernel: probe_iou writes junk to iou_out,
    // conv_iou_kernel then overwrites every element with correct values.
    probe_front<<<B_ * NTILE, 256, 0, stream>>>(features, w1s, b1, w2s);
    probe_iou<<<B_ * A_ * NTILE, 256, 0, stream>>>(bboxes, out + 1);
    conv_iou_kernel<<<B_ * NTILE, 256, 0, stream>>>(features, w1s, b1, w2s, b2,
                                                    anc, bboxes, pcnt, ncnt, pbuf, nbuf,
                                                    gt_off, out + 1,
                                                    out + 1 + IOU_N, loss_ws);
    finalize_kernel<<<1, 1, 0, stream>>>(loss_ws, out);
}

// Round 8
// 432.348 us; speedup vs baseline: 1.4320x; 1.4320x over previous
//
#include <hip/hip_runtime.h>
#include <math.h>

#define B_    32
#define CIN   256
#define HID   256
#define OC    65
#define A_    9
#define H_    56
#define W_    56
#define HW    3136
#define AHW   28224
#define NBOX  64
#define M_    2048
#define CNUM  20
#define NTILE 49         // HW / 64
#define NTILES_TOT (B_ * NTILE)              // 1568
#define NSLOT 25         // tile-pair slots per batch (slot 24 = single tile 48)

#define IOU_N ((size_t)B_ * AHW * NBOX)      // 57,802,752

// workspace byte offsets (total < 1 MB)
#define WS_W1S   0
#define WS_W2S   131072
#define WS_LOSS  172032
#define WS_PCNT  172288
#define WS_NCNT  178560
#define WS_PBUF  184832
#define WS_NBUF  586240

// padded LDS fragment offset (halfwords): +16B every 8 fragment rows.
#define FOFF(frag) (((frag) << 3) + ((((frag) >> 3)) << 3))

typedef _Float16 half8 __attribute__((ext_vector_type(8)));
typedef float f32x16 __attribute__((ext_vector_type(16)));
typedef float f32x4  __attribute__((ext_vector_type(4)));

__device__ __forceinline__ unsigned int pkh(float a, float b) {
    _Float16 ha = (_Float16)a, hb = (_Float16)b;
    unsigned short ua = __builtin_bit_cast(unsigned short, ha);
    unsigned short ub = __builtin_bit_cast(unsigned short, hb);
    return (unsigned int)ua | ((unsigned int)ub << 16);
}

// LDS-only phase barrier: orders all cross-wave LDS traffic WITHOUT draining
// the VMEM queue (global loads/stores stay in flight across it). This is the
// whole point of round 8: __syncthreads() emits s_waitcnt vmcnt(0) before
// s_barrier, which forced every phase to pay its memory latency serially.
__device__ __forceinline__ void phase_barrier() {
    __builtin_amdgcn_sched_barrier(0);
    asm volatile("s_waitcnt lgkmcnt(0)" ::: "memory");
    __builtin_amdgcn_s_barrier();
    __builtin_amdgcn_sched_barrier(0);
}

__global__ __launch_bounds__(256) void zero_kernel(int* __restrict__ cnts,
                                                   float* __restrict__ loss_ws) {
    const int i = blockIdx.x * 256 + threadIdx.x;
    if (i < 2 * NTILES_TOT) cnts[i] = 0;
    if (i < 2) loss_ws[i] = 0.f;
}

// Pre-swizzle weights into MFMA A-fragment order (fp16); bucket pos/neg indices by tile.
__global__ __launch_bounds__(256) void prep_kernel(
    const float* __restrict__ w1, const float* __restrict__ w2,
    _Float16* __restrict__ w1s, _Float16* __restrict__ w2s,
    const int* __restrict__ pos_idx, const int* __restrict__ neg_idx,
    int* __restrict__ pcnt, int* __restrict__ ncnt,
    int* __restrict__ pbuf, int* __restrict__ nbuf)
{
    const int f = blockIdx.x * 256 + threadIdx.x;   // 0..65535
    {
        const int e    = f & 7;
        const int lane = (f >> 3) & 63;
        const int kc   = (f >> 9) & 15;
        const int ob   = f >> 13;
        const int row  = ob * 32 + (lane & 31);
        const int k    = kc * 16 + (lane >> 5) * 8 + e;
        w1s[f] = (_Float16)w1[row * CIN + k];
    }
    if (f < 20480) {
        const int e    = f & 7;
        const int lane = (f >> 3) & 63;
        const int ks2  = (f >> 9) & 7;
        const int rt   = f >> 12;
        const int row  = rt * 16 + (lane & 15);
        const int k    = ks2 * 32 + (lane >> 4) * 8 + e;
        w2s[f] = (row < OC) ? (_Float16)w2[row * HID + k] : (_Float16)0.f;
    }
    if (f < 2 * M_) {
        const int m   = f & (M_ - 1);
        const int idx = (f < M_) ? pos_idx[m] : neg_idx[m];
        const int bi  = idx / AHW;
        const int rr  = idx - bi * AHW;
        const int a   = rr / HW;
        const int hw  = rr - a * HW;
        const int tile = bi * NTILE + (hw >> 6);
        const int enc  = m | (a << 11) | ((hw & 63) << 15);
        if (f < M_) {
            const int s = atomicAdd(&pcnt[tile], 1);
            if (s < 64) pbuf[tile * 64 + s] = enc;
        } else {
            const int s = atomicAdd(&ncnt[tile], 1);
            if (s < 64) nbuf[tile * 64 + s] = enc;
        }
    }
}

// Issue the 16 coalesced float4 feature loads for one tile (registers only).
__device__ __forceinline__ void stage_issue(const float* __restrict__ fbase,
                                            int kk, int pstage,
                                            float4* __restrict__ s0,
                                            float4* __restrict__ s1)
{
#pragma unroll
    for (int c = 0; c < 8; ++c) {
        s0[c] = *(const float4*)(fbase + (size_t)(c * 32 + kk) * HW + pstage);
        s1[c] = *(const float4*)(fbase + (size_t)(c * 32 + kk + 1) * HW + pstage);
    }
}

// Convert staged regs fp32->fp16 and scatter into padded fragment order.
__device__ __forceinline__ void stage_store(_Float16* __restrict__ featAll,
                                            int pstage, int ksS, int gS, int j0h,
                                            const float4* __restrict__ s0,
                                            const float4* __restrict__ s1)
{
#pragma unroll
    for (int c = 0; c < 8; ++c) {
        const float a0[4] = {s0[c].x, s0[c].y, s0[c].z, s0[c].w};
        const float a1[4] = {s1[c].x, s1[c].y, s1[c].z, s1[c].w};
#pragma unroll
        for (int e = 0; e < 4; ++e) {
            const int p     = pstage + e;
            const int lane2 = gS * 32 + (p & 31);
            const int pt    = p >> 5;
            const int frag  = c * 256 + (ksS * 2 + pt) * 64 + lane2;
            *(unsigned int*)&featAll[FOFF(frag) + j0h] = pkh(a0[e], a1[e]);
        }
    }
}

// Fused conv1 + conv2 + IoU + bucketed loss/class tail, TWO-TILE PIPELINE:
// each block handles tiles (b, 2*slot) and (b, 2*slot+1). Tile i+1's staging
// loads issue after conv2(i); all internal barriers are LDS-only (no vmcnt
// drain) so staging latency hides under IoU(i) and IoU(i) stores drain under
// conv1(i+1) MFMAs.
__global__ __launch_bounds__(256) void conv_iou_kernel(
    const float* __restrict__ features, const _Float16* __restrict__ w1s,
    const float* __restrict__ b1, const _Float16* __restrict__ w2s,
    const float* __restrict__ b2, const float* __restrict__ anc,
    const float* __restrict__ bboxes,
    const int* __restrict__ pcnt, const int* __restrict__ ncnt,
    const int* __restrict__ pbuf, const int* __restrict__ nbuf,
    const float* __restrict__ gt_off,
    float* __restrict__ iou_out, float* __restrict__ cls_out,
    float* __restrict__ loss_ws)
{
    __shared__ _Float16 lds_h[18432];   // 36 KB: feat frags -> hidf -> x2t+WP
    __shared__ float bias_s[HID];
    __shared__ float boxs[5 * 64];
    __shared__ float red[8];

    _Float16* featAll = lds_h;
    _Float16* hidf    = lds_h;
    float*    L       = (float*)lds_h;
    float*    x2t     = L;              // 64*69 floats

    const int t    = threadIdx.x;
    const int lane = t & 63;
    const int w    = t >> 6;
    const int bid  = blockIdx.x;
    const int b    = bid / NSLOT;
    const int slot = bid - b * NSLOT;
    const int j0t  = slot * 2;
    const int ntiles = (slot < NSLOT - 1) ? 2 : 1;
    const float* fb0 = features + (size_t)b * CIN * HW;

    float* WPw = L + 4416 + w * 720;    // per-wave proposals: 5 planes x 144

    bias_s[t] = b1[t];
    if (t < 64) {
        const float* gb = bboxes + ((size_t)b * NBOX + t) * 5;
        const float x1 = gb[0], y1 = gb[1], x2v = gb[2], y2v = gb[3];
        boxs[t] = x1; boxs[64 + t] = y1; boxs[128 + t] = x2v; boxs[192 + t] = y2v;
        boxs[256 + t] = (x2v - x1) * (y2v - y1);
    }

    const int pstage = (t & 15) * 4;
    const int kk     = (t >> 4) * 2;
    const int ksS    = kk >> 4;
    const int gS     = (kk >> 3) & 1;
    const int j0h    = kk & 7;
    const int ghalf  = lane >> 5;
    const int col    = lane & 31;
    const int m16    = lane & 15;
    const int kgr    = lane >> 4;
    const int pr     = lane >> 4;
    const int j0     = (lane & 15) * 4;

    float Bx1[4], By1[4], Bx2[4], By2[4], Ba[4];   // filled after first barrier

    // issue tile-0 staging loads immediately
    float4 s0[8], s1[8];
    stage_issue(fb0 + j0t * 64, kk, pstage, s0, s1);

    float csum = 0.f, rsum = 0.f;

    for (int it = 0; it < ntiles; ++it) {
        const int p0 = (j0t + it) * 64;

        // ---- convert staged regs -> featAll (vmcnt waits auto-inserted) ----
        stage_store(featAll, pstage, ksS, gS, j0h, s0, s1);
        phase_barrier();   // B1: featAll writes visible

        if (it == 0) {
            // boxs is stable from here on (written before B1)
#pragma unroll
            for (int e = 0; e < 4; ++e) {
                Bx1[e] = boxs[j0 + e];       By1[e] = boxs[64 + j0 + e];
                Bx2[e] = boxs[128 + j0 + e]; By2[e] = boxs[192 + j0 + e];
                Ba[e]  = boxs[256 + j0 + e];
            }
        }

        // ---- conv1: wave w -> hidden rows [64w,64w+64) ----
        f32x16 facc[2][2];
#pragma unroll
        for (int ot = 0; ot < 2; ++ot)
#pragma unroll
            for (int pt = 0; pt < 2; ++pt)
#pragma unroll
                for (int e = 0; e < 16; ++e) facc[ot][pt][e] = 0.f;

        half8 afb[2][2][2];
#pragma unroll
        for (int ks = 0; ks < 2; ++ks)
#pragma unroll
            for (int ot = 0; ot < 2; ++ot)
                afb[0][ks][ot] = *(const half8*)(w1s + ((size_t)((w * 2 + ot) * 16 + ks) * 64 + lane) * 8);

#pragma unroll
        for (int c = 0; c < 8; ++c) {
            if (c < 7) {
#pragma unroll
                for (int ks = 0; ks < 2; ++ks)
#pragma unroll
                    for (int ot = 0; ot < 2; ++ot)
                        afb[(c + 1) & 1][ks][ot] =
                            *(const half8*)(w1s + ((size_t)((w * 2 + ot) * 16 + (c + 1) * 2 + ks) * 64 + lane) * 8);
            }
#pragma unroll
            for (int ks = 0; ks < 2; ++ks) {
#pragma unroll
                for (int pt = 0; pt < 2; ++pt) {
                    const half8 bf = *(const half8*)&featAll[FOFF(c * 256 + (ks * 2 + pt) * 64 + lane)];
                    facc[0][pt] = __builtin_amdgcn_mfma_f32_32x32x16_f16(afb[c & 1][ks][0], bf, facc[0][pt], 0, 0, 0);
                    facc[1][pt] = __builtin_amdgcn_mfma_f32_32x32x16_f16(afb[c & 1][ks][1], bf, facc[1][pt], 0, 0, 0);
                }
            }
        }
        phase_barrier();   // B2: featAll reads done -> hidf writes may begin

        // ---- bias + leaky relu, repack to conv2 B-fragment order ----
#pragma unroll
        for (int ot = 0; ot < 2; ++ot) {
            const int ks2 = w * 2 + ot;
#pragma unroll
            for (int pt = 0; pt < 2; ++pt) {
                const int pt2 = pt * 2 + (col >> 4);
                const int n15 = col & 15;
#pragma unroll
                for (int q = 0; q < 4; ++q) {
                    float hv[4];
#pragma unroll
                    for (int i = 0; i < 4; ++i) {
                        const int row = i + 8 * q + 4 * ghalf;
                        float v = facc[ot][pt][q * 4 + i] + bias_s[w * 64 + ot * 32 + row];
                        hv[i] = v < 0.f ? 0.01f * v : v;
                    }
                    const int frag = (ks2 * 4 + pt2) * 64 + (q * 16 + n15);
                    *(unsigned int*)&hidf[FOFF(frag) + 4 * ghalf]     = pkh(hv[0], hv[1]);
                    *(unsigned int*)&hidf[FOFF(frag) + 4 * ghalf + 2] = pkh(hv[2], hv[3]);
                }
            }
        }
        phase_barrier();   // B3: hidf writes visible

        // ---- conv2 via 16x16x32 MFMA; wave w owns pixels [16w,16w+16) ----
        f32x4 c2[5];
#pragma unroll
        for (int rt = 0; rt < 5; ++rt)
#pragma unroll
            for (int e = 0; e < 4; ++e) c2[rt][e] = 0.f;

        half8 afc[2][5];
#pragma unroll
        for (int rt = 0; rt < 5; ++rt)
            afc[0][rt] = *(const half8*)(w2s + ((size_t)(rt * 8) * 64 + lane) * 8);

#pragma unroll
        for (int ks2 = 0; ks2 < 8; ++ks2) {
            if (ks2 < 7) {
#pragma unroll
                for (int rt = 0; rt < 5; ++rt)
                    afc[(ks2 + 1) & 1][rt] =
                        *(const half8*)(w2s + ((size_t)(rt * 8 + ks2 + 1) * 64 + lane) * 8);
            }
            const half8 bf = *(const half8*)&hidf[FOFF((ks2 * 4 + w) * 64 + lane)];
#pragma unroll
            for (int rt = 0; rt < 5; ++rt)
                c2[rt] = __builtin_amdgcn_mfma_f32_16x16x32_f16(afc[ks2 & 1][rt], bf, c2[rt], 0, 0, 0);
        }

        // ---- EARLY ISSUE: next tile's staging loads (regs only, no LDS) ----
        if (it + 1 < ntiles)
            stage_issue(fb0 + (p0 + 64), kk, pstage, s0, s1);

        phase_barrier();   // B4: hidf reads done -> x2t writes may begin

        // ---- x2 tile (wave-local rows) ----
        const int pxl = w * 16 + m16;
#pragma unroll
        for (int rt = 0; rt < 5; ++rt) {
#pragma unroll
            for (int r = 0; r < 4; ++r) {
                const int o2 = rt * 16 + kgr * 4 + r;
                if (o2 < OC) x2t[pxl * 69 + o2] = c2[rt][r] + b2[o2];
            }
        }
        asm volatile("" ::: "memory");   // same-wave DS order

        // ---- proposals for THIS wave's 16 pixels x 9 anchors ----
        for (int i = lane; i < A_ * 16; i += 64) {
            const int a  = i >> 4;
            const int pw = i & 15;
            const float* xr = x2t + (w * 16 + pw) * 69 + 5 * a;
            const float tx = xr[1], ty = xr[2], tw = xr[3], th = xr[4];
            const int hwg = p0 + w * 16 + pw;
            const int h   = hwg / W_;
            const int wv  = hwg - h * W_;
            const float gx = (float)wv + 0.5f;
            const float gy = (float)h + 0.5f;
            const float nw = anc[2 * a]     * __expf(tw);
            const float nh = anc[2 * a + 1] * __expf(th);
            const float cx = gx + tx, cy = gy + ty;
            WPw[i]       = cx - 0.5f * nw;
            WPw[144 + i] = cy - 0.5f * nh;
            WPw[288 + i] = cx + 0.5f * nw;
            WPw[432 + i] = cy + 0.5f * nh;
            WPw[576 + i] = nw * nh;
        }
        asm volatile("" ::: "memory");

        // ---- IoU stream-out (stores stay in flight across B5/B6) ----
        float* ibase = iou_out + ((size_t)b * AHW + p0) * 64;
#pragma unroll 1
        for (int a = 0; a < A_; ++a) {
            float Px1[4], Py1[4], Px2[4], Py2[4], Pa[4];
#pragma unroll
            for (int q = 0; q < 4; ++q) {
                const int idx = a * 16 + q * 4 + pr;
                Px1[q] = WPw[idx];       Py1[q] = WPw[144 + idx];
                Px2[q] = WPw[288 + idx]; Py2[q] = WPw[432 + idx];
                Pa[q]  = WPw[576 + idx];
            }
#pragma unroll
            for (int q = 0; q < 4; ++q) {
                f32x4 o4;
#pragma unroll
                for (int e = 0; e < 4; ++e) {
                    const float iw = fminf(Px2[q], Bx2[e]) - fmaxf(Px1[q], Bx1[e]);
                    const float ih = fminf(Py2[q], By2[e]) - fmaxf(Py1[q], By1[e]);
                    const float inter = fmaxf(iw, 0.f) * fmaxf(ih, 0.f);
                    o4[e] = inter * __builtin_amdgcn_rcpf(Ba[e] + Pa[q] - inter);
                }
                *(f32x4*)(ibase + ((size_t)(a * HW) + w * 16 + q * 4 + pr) * 64 + j0) = o4;
            }
        }

        phase_barrier();   // B5: all waves' x2t writes visible for the tail

        // ---- bucketed loss/class tail for this tile ----
        {
            const int bidt = b * NTILE + j0t + it;
            int np = pcnt[bidt]; np = np > 64 ? 64 : np;
            for (int i = t; i < np; i += 256) {
                const int e  = pbuf[bidt * 64 + i];
                const int m  = e & 2047;
                const int a  = (e >> 11) & 15;
                const int px = (e >> 15) & 63;
                const float* xr = x2t + px * 69;
                const float s = 1.f / (1.f + __expf(-xr[5 * a]));
                csum += (s - 1.f) * (s - 1.f);
#pragma unroll
                for (int k = 0; k < 4; ++k) {
                    const float d = xr[5 * a + 1 + k] - gt_off[m * 4 + k];
                    rsum += d * d;
                }
                float* co = cls_out + (size_t)m * CNUM;
#pragma unroll
                for (int c = 0; c < CNUM; ++c) co[c] = xr[45 + c];
            }
            int nn = ncnt[bidt]; nn = nn > 64 ? 64 : nn;
            for (int i = t; i < nn; i += 256) {
                const int e  = nbuf[bidt * 64 + i];
                const int a  = (e >> 11) & 15;
                const int px = (e >> 15) & 63;
                const float s = 1.f / (1.f + __expf(-x2t[px * 69 + 5 * a]));
                csum += s * s;
            }
        }
        phase_barrier();   // B6: x2t reads done -> next stage_store may overwrite
    }

    // ---- final block reduction + one atomic ----
#pragma unroll
    for (int off = 32; off > 0; off >>= 1) {
        csum += __shfl_down(csum, off, 64);
        rsum += __shfl_down(rsum, off, 64);
    }
    if (lane == 0) { red[w] = csum; red[4 + w] = rsum; }
    __syncthreads();
    if (t == 0) {
        const float c  = red[0] + red[1] + red[2] + red[3];
        const float rg = red[4] + red[5] + red[6] + red[7];
        if (c != 0.f || rg != 0.f) {
            atomicAdd(&loss_ws[0], c);
            atomicAdd(&loss_ws[1], rg);
        }
    }
}

__global__ void finalize_kernel(const float* __restrict__ loss_ws, float* __restrict__ out0)
{
    out0[0] = loss_ws[0] / (2.f * (float)M_) + loss_ws[1] / (float)M_;
}

extern "C" void kernel_launch(void* const* d_in, const int* in_sizes, int n_in,
                              void* d_out, int out_size, void* d_ws, size_t ws_size,
                              hipStream_t stream) {
    (void)in_sizes; (void)n_in; (void)out_size; (void)ws_size;
    const float* features = (const float*)d_in[0];
    const float* w1       = (const float*)d_in[1];
    const float* b1       = (const float*)d_in[2];
    const float* w2       = (const float*)d_in[3];
    const float* b2       = (const float*)d_in[4];
    const float* anc      = (const float*)d_in[5];
    const float* bboxes   = (const float*)d_in[7];
    const float* gt_off   = (const float*)d_in[8];
    const int*   pos_idx  = (const int*)d_in[9];
    const int*   neg_idx  = (const int*)d_in[10];
    float* out = (float*)d_out;

    char* wsb = (char*)d_ws;
    _Float16* w1s  = (_Float16*)(wsb + WS_W1S);
    _Float16* w2s  = (_Float16*)(wsb + WS_W2S);
    float* loss_ws = (float*)(wsb + WS_LOSS);
    int*   pcnt    = (int*)(wsb + WS_PCNT);
    int*   ncnt    = (int*)(wsb + WS_NCNT);
    int*   pbuf    = (int*)(wsb + WS_PBUF);
    int*   nbuf    = (int*)(wsb + WS_NBUF);

    zero_kernel<<<13, 256, 0, stream>>>(pcnt, loss_ws);
    prep_kernel<<<256, 256, 0, stream>>>(w1, w2, w1s, w2s, pos_idx, neg_idx,
                                         pcnt, ncnt, pbuf, nbuf);
    conv_iou_kernel<<<B_ * NSLOT, 256, 0, stream>>>(features, w1s, b1, w2s, b2,
                                                    anc, bboxes, pcnt, ncnt, pbuf, nbuf,
                                                    gt_off, out + 1,
                                                    out + 1 + IOU_N, loss_ws);
    finalize_kernel<<<1, 1, 0, stream>>>(loss_ws, out);
}